// Round 20
// baseline (194.087 us; speedup 1.0000x reference)
//
#include <hip/hip_runtime.h>
#include <hip/hip_bf16.h>
#include <math.h>

// Problem: B=4, T=2048, C=1024, H=16, D=64
// out = proj( attention( x @ W_attn + b_attn ) ) + b_proj

typedef __bf16 bf16x8 __attribute__((ext_vector_type(8)));
typedef float f32x4 __attribute__((ext_vector_type(4)));
typedef float f32x16 __attribute__((ext_vector_type(16)));

__device__ __forceinline__ f32x4 mfma16(bf16x8 a, bf16x8 b, f32x4 c) {
    return __builtin_amdgcn_mfma_f32_16x16x32_bf16(a, b, c, 0, 0, 0);
}
__device__ __forceinline__ f32x16 mfma32(bf16x8 a, bf16x8 b, f32x16 c) {
    return __builtin_amdgcn_mfma_f32_32x32x16_bf16(a, b, c, 0, 0, 0);
}

#define GLOBAL_AS __attribute__((address_space(1)))
#define LDS_AS __attribute__((address_space(3)))

// async 16B/lane global->LDS (dest is wave-uniform base + lane*16)
__device__ __forceinline__ void async_copy16(const __hip_bfloat16* g, __hip_bfloat16* l) {
    __builtin_amdgcn_global_load_lds((const GLOBAL_AS uint32_t*)g, (LDS_AS uint32_t*)l, 16, 0, 0);
}

// pack two f32 -> 2 bf16 in one u32 (lo = first arg)
__device__ __forceinline__ uint32_t cvtpk(float lo, float hi) {
    uint32_t r;
    asm("v_cvt_pk_bf16_f32 %0, %1, %2" : "=v"(r) : "v"(lo), "v"(hi));
    return r;
}

// q is pre-scaled by 0.125*log2(e) so softmax exps are pure exp2
#define QSCL 0.18033688011112042f

// ---- fused preprocessing: cast x + transpose both weight matrices ----
__global__ __launch_bounds__(256) void prep_kernel(
    const float* __restrict__ x, __hip_bfloat16* __restrict__ xb,
    const float* __restrict__ Wa, __hip_bfloat16* __restrict__ WaT,
    const float* __restrict__ Wp, __hip_bfloat16* __restrict__ WpT) {
    int bid = blockIdx.x;
    if (bid < 4096) {
        int i = (bid * 256 + threadIdx.x) * 8;
        union { __hip_bfloat16 h[8]; uint4 v; } tmp;
#pragma unroll
        for (int j = 0; j < 8; ++j) tmp.h[j] = __float2bfloat16(x[i + j]);
        *reinterpret_cast<uint4*>(xb + i) = tmp.v;
        return;
    }
    __shared__ float tile[32][33];
    const float* in;
    __hip_bfloat16* out;
    int R, Cc, tx_blocks, tb;
    if (bid < 4096 + 3072) {
        tb = bid - 4096; in = Wa; out = WaT; R = 1024; Cc = 3072; tx_blocks = 96;
    } else {
        tb = bid - 4096 - 3072; in = Wp; out = WpT; R = 1024; Cc = 1024; tx_blocks = 32;
    }
    int c0 = (tb % tx_blocks) * 32, r0 = (tb / tx_blocks) * 32;
    int tx = threadIdx.x & 31, ty = threadIdx.x >> 5;  // ty 0..7
#pragma unroll
    for (int i = 0; i < 4; ++i) {
        int r = r0 + ty + i * 8;
        tile[ty + i * 8][tx] = in[(size_t)r * Cc + c0 + tx];
    }
    __syncthreads();
#pragma unroll
    for (int i = 0; i < 4; ++i) {
        int c = c0 + ty + i * 8;
        out[(size_t)c * R + r0 + tx] = __float2bfloat16(tile[tx][ty + i * 8]);
    }
}

// ================= m97-style 128x128 GEMM core (R15 form, proven 728 TF) =========
#define GEMM128_BODY(A_, Bt_, K_)                                                       \
    __shared__ __hip_bfloat16 As[128 * 32];                                             \
    __shared__ __hip_bfloat16 Bs[128 * 32];                                             \
    const int tid = threadIdx.x;                                                        \
    const int w = tid >> 6;                                                             \
    const int lr = tid & 15, lh = (tid & 63) >> 4;                                      \
    const int wr = w >> 1, wc = w & 1;                                                  \
    f32x4 zero = {0.f, 0.f, 0.f, 0.f};                                                  \
    f32x4 acc[4][4];                                                                    \
    _Pragma("unroll") for (int i = 0; i < 4; ++i)                                       \
        _Pragma("unroll") for (int j = 0; j < 4; ++j) acc[i][j] = zero;                 \
    for (int k0 = 0; k0 < (K_); k0 += 32) {                                             \
        _Pragma("unroll") for (int i = 0; i < 2; ++i) {                                 \
            int t = i * 256 + tid;                                                      \
            async_copy16((A_) + (size_t)(m0 + (t >> 2)) * (K_) + k0 + (t & 3) * 8,      \
                         As + (size_t)(i * 256 + w * 64) * 8);                          \
            async_copy16((Bt_) + (size_t)(n0 + (t >> 2)) * (K_) + k0 + (t & 3) * 8,     \
                         Bs + (size_t)(i * 256 + w * 64) * 8);                          \
        }                                                                               \
        __syncthreads();                                                                \
        bf16x8 af[4], bf[4];                                                            \
        _Pragma("unroll") for (int mf = 0; mf < 4; ++mf)                                \
            af[mf] = *reinterpret_cast<const bf16x8*>(                                  \
                &As[(wr * 64 + mf * 16 + lr) * 32 + lh * 8]);                           \
        _Pragma("unroll") for (int nf = 0; nf < 4; ++nf)                                \
            bf[nf] = *reinterpret_cast<const bf16x8*>(                                  \
                &Bs[(wc * 64 + nf * 16 + lr) * 32 + lh * 8]);                           \
        _Pragma("unroll") for (int mf = 0; mf < 4; ++mf)                                \
            _Pragma("unroll") for (int nf = 0; nf < 4; ++nf)                            \
                acc[mf][nf] = mfma16(af[mf], bf[nf], acc[mf][nf]);                      \
        __syncthreads();                                                                \
    }

// ---- QKV GEMM ----
__global__ __launch_bounds__(256) void gemm_qkv_kernel(
    const __hip_bfloat16* __restrict__ A, const __hip_bfloat16* __restrict__ Bt,
    const float* __restrict__ bias,
    __hip_bfloat16* __restrict__ qd, __hip_bfloat16* __restrict__ kd,
    __hip_bfloat16* __restrict__ vtd) {
    const int K = 1024;
    const int m0 = blockIdx.x * 128;
    const int n0 = blockIdx.y * 128;
    GEMM128_BODY(A, Bt, K)

    const int region = n0 >> 10;  // 0:q 1:k 2:v (block-uniform)
#pragma unroll
    for (int mf = 0; mf < 4; ++mf) {
#pragma unroll
        for (int nf = 0; nf < 4; ++nf) {
            int n = n0 + wc * 64 + nf * 16 + lr;
            float bv = bias[n];
            int mbase = m0 + wr * 64 + mf * 16 + 4 * lh;
            int bb = mbase >> 11;
            int t = mbase & 2047;
            int c = n & 1023, hh = c >> 6, dd = c & 63;
            if (region == 2) {
                union { __hip_bfloat16 h[4]; uint2 v; } pk;
#pragma unroll
                for (int r = 0; r < 4; ++r) pk.h[r] = __float2bfloat16(acc[mf][nf][r] + bv);
                *reinterpret_cast<uint2*>(
                    &vtd[(((size_t)bb * 16 + hh) * 64 + dd) * 2048 + t]) = pk.v;
            } else if (region == 0) {
#pragma unroll
                for (int r = 0; r < 4; ++r)
                    qd[(((size_t)bb * 16 + hh) * 2048 + t + r) * 64 + dd] =
                        __float2bfloat16((acc[mf][nf][r] + bv) * QSCL);
            } else {
#pragma unroll
                for (int r = 0; r < 4; ++r)
                    kd[(((size_t)bb * 16 + hh) * 2048 + t + r) * 64 + dd] =
                        __float2bfloat16(acc[mf][nf][r] + bv);
            }
        }
    }
}

// ---- proj GEMM ----
__global__ __launch_bounds__(256) void gemm_proj_kernel(
    const __hip_bfloat16* __restrict__ A, const __hip_bfloat16* __restrict__ Bt,
    const float* __restrict__ bias, float* __restrict__ out) {
    const int K = 1024, N = 1024;
    const int m0 = blockIdx.x * 128;
    const int n0 = blockIdx.y * 128;
    GEMM128_BODY(A, Bt, K)

#pragma unroll
    for (int nf = 0; nf < 4; ++nf) {
        int n = n0 + wc * 64 + nf * 16 + lr;
        float bv = bias[n];
#pragma unroll
        for (int mf = 0; mf < 4; ++mf) {
            int mbase = m0 + wr * 64 + mf * 16 + 4 * lh;
#pragma unroll
            for (int r = 0; r < 4; ++r)
                out[(size_t)(mbase + r) * N + n] = acc[mf][nf][r] + bv;
        }
    }
}

// ---- causal flash attention v15: v14 with KVBLK=128 (half the barrier cadence) ----
// Block = 512 threads = 8 waves x 32 q-rows. Per stage: K[128 kv][64 d] (16KB,
// 128B rows) + V^T[64 d][128 kv] (16KB, 256B rows), both fold-swizzled
// (write-side pre-swizzled source, read-side same XOR). 4 compute sub-steps per
// stage (was 2) -> stage/barrier/drain count exactly halves: nt128 = 2*q256+2.
// Per-CU stage work stays uniform (complementary q256 pairing).
__global__ __launch_bounds__(512) void attn_kernel(
    const __hip_bfloat16* __restrict__ q, const __hip_bfloat16* __restrict__ k,
    const __hip_bfloat16* __restrict__ vt, __hip_bfloat16* __restrict__ y) {
    const int T = 2048, D = 64, C = 1024;
    const float THR = 8.0f;

    // XCD swizzle: 64 consecutive wids per XCD = 8 whole heads
    int wid = ((int)blockIdx.x & 7) * 64 + ((int)blockIdx.x >> 3);
    int bh = wid >> 3;
    int qr = wid & 7;
    int q256 = (wid & 32) ? qr : 7 - qr;  // complementary across co-resident blocks
    int b = bh >> 4, h = bh & 15;
    int tid = threadIdx.x;
    int w = tid >> 6, l = tid & 63;
    int ql = l & 31, hi = l >> 5;

    __shared__ __hip_bfloat16 Ks[128 * 64];     // [kv][d], 128B rows, fold-swizzled
    __shared__ __hip_bfloat16 Vs[64 * 128];     // [d][kv], 256B rows, fold-swizzled
    __shared__ __hip_bfloat16 Pt[8][32][36];    // per-wave transposed P (R11-verified)

    const int q0 = q256 * 256 + w * 32;
    const __hip_bfloat16* kbh = k + (size_t)bh * T * D;
    const __hip_bfloat16* vbh = vt + (size_t)bh * D * T;

    // Q B-frags (hoisted): frag c covers d = c*16 + hi*8 .. +8, col = q0+ql
    bf16x8 qf[4];
#pragma unroll
    for (int c = 0; c < 4; ++c)
        qf[c] = *reinterpret_cast<const bf16x8*>(
            q + ((size_t)bh * T + q0 + ql) * D + c * 16 + hi * 8);

    f32x16 o0 = {}, o1 = {};
    float m = -INFINITY, lp = 0.f;

    const int lastSub = q0 >> 5;      // last active 32-kv sub-tile for this wave
    const int nt128 = 2 * q256 + 2;   // block-uniform outer stage count (128 kv each)

    for (int t128 = 0; t128 < nt128; ++t128) {
        __syncthreads();  // previous stage's LDS reads complete before overwrite
        // ---- stage K (16KB) + V^T (16KB): 512 thr x 2 K slots + 2 V slots ----
#pragma unroll
        for (int j = 0; j < 2; ++j) {
            int slot = j * 512 + tid;                              // 0..1023
            // K: row = kv 0..127 (128B rows, 8 slots/row)
            int krow = slot >> 3;
            int kfold = ((krow & 7) ^ ((krow >> 3) & 7)) & 7;
            int kcolb = ((slot & 7) * 16) ^ (kfold << 4);
            async_copy16(kbh + (size_t)(t128 * 128 + krow) * 64 + (kcolb >> 1),
                         Ks + (size_t)(j * 512 + w * 64) * 8);
            // V: row = d 0..63 (256B rows, 16 slots/row)
            int vrow = slot >> 4;
            int vfold = ((vrow & 7) ^ ((vrow >> 3) & 7)) & 7;
            int vcolb = ((slot & 15) * 16) ^ (vfold << 4);
            async_copy16(vbh + (size_t)vrow * T + t128 * 128 + (vcolb >> 1),
                         Vs + (size_t)(j * 512 + w * 64) * 8);
        }
        __syncthreads();  // drains vmcnt, stage visible

#pragma unroll
        for (int sub = 0; sub < 4; ++sub) {
            const int is = t128 * 4 + sub;
            if (is > lastSub) break;   // wave-uniform causal skip
            // K frags from LDS: row = sub*32+ql (0..127), d-chunk c*16+hi*8
            bf16x8 kf[4];
            {
                int krow = sub * 32 + ql;
                int kfold = ((krow & 7) ^ ((krow >> 3) & 7)) & 7;
                const char* KsB = reinterpret_cast<const char*>(Ks) + krow * 128;
#pragma unroll
                for (int c = 0; c < 4; ++c)
                    kf[c] = *reinterpret_cast<const bf16x8*>(
                        KsB + ((c * 32 + hi * 16) ^ (kfold << 4)));
            }

            __builtin_amdgcn_s_setprio(1);
            f32x16 s = {};
            s = mfma32(kf[0], qf[0], s);
            s = mfma32(kf[1], qf[1], s);
            s = mfma32(kf[2], qf[2], s);
            s = mfma32(kf[3], qf[3], s);
            __builtin_amdgcn_s_setprio(0);

            // V frags from LDS: row d = dblk*32+ql (256B rows), kv-chunk sub*64..+
            bf16x8 vf[2][2];
#pragma unroll
            for (int dblk = 0; dblk < 2; ++dblk) {
                int vrow = dblk * 32 + ql;
                int vfold = ((vrow & 7) ^ ((vrow >> 3) & 7)) & 7;
                const char* VsB = reinterpret_cast<const char*>(Vs) + vrow * 256;
#pragma unroll
                for (int sl = 0; sl < 2; ++sl)
                    vf[dblk][sl] = *reinterpret_cast<const bf16x8*>(
                        VsB + ((sub * 64 + sl * 32 + hi * 16) ^ (vfold << 4)));
            }

            // causal mask (diagonal sub-tile only): kv row > q row
            if (is == lastSub) {
#pragma unroll
                for (int r = 0; r < 16; ++r) {
                    int kvrow = (r & 3) + 8 * (r >> 2) + 4 * hi;
                    if (kvrow > ql) s[r] = -INFINITY;
                }
            }

            // row max: max3-friendly tree in-lane, then cross-half combine
            float mx;
            {
                float a = fmaxf(fmaxf(s[0], s[1]), s[2]);
                float bq = fmaxf(fmaxf(s[3], s[4]), s[5]);
                float c = fmaxf(fmaxf(s[6], s[7]), s[8]);
                float d = fmaxf(fmaxf(s[9], s[10]), s[11]);
                float e = fmaxf(fmaxf(s[12], s[13]), s[14]);
                mx = fmaxf(fmaxf(fmaxf(a, bq), fmaxf(c, d)), fmaxf(e, s[15]));
            }
            mx = fmaxf(mx, __shfl_xor(mx, 32));

            // defer-max: rescale only when growth exceeds THR
            if (!__all(mx - m <= THR)) {
                float mnew = fmaxf(m, mx);
                float al = __builtin_amdgcn_exp2f(m - mnew);
                m = mnew;
                lp *= al;
#pragma unroll
                for (int r = 0; r < 16; ++r) { o0[r] *= al; o1[r] *= al; }
            }

            // p = exp2(s - m)
#pragma unroll
            for (int r = 0; r < 16; ++r) s[r] = __builtin_amdgcn_exp2f(s[r] - m);

            // per-lane partial row sum (combined with partner at epilogue)
            lp += ((s[0] + s[1]) + (s[2] + s[3])) + ((s[4] + s[5]) + (s[6] + s[7])) +
                  (((s[8] + s[9]) + (s[10] + s[11])) + ((s[12] + s[13]) + (s[14] + s[15])));

            // stage P transposed: s[4g+r] = P[kv = 8g+4hi+r][q0+ql] -> Pt[ql][8g+4hi+r]
            {
                uint2 w0, w1, w2, w3;
                w0.x = cvtpk(s[0], s[1]);   w0.y = cvtpk(s[2], s[3]);
                w1.x = cvtpk(s[4], s[5]);   w1.y = cvtpk(s[6], s[7]);
                w2.x = cvtpk(s[8], s[9]);   w2.y = cvtpk(s[10], s[11]);
                w3.x = cvtpk(s[12], s[13]); w3.y = cvtpk(s[14], s[15]);
                *reinterpret_cast<uint2*>(&Pt[w][ql][4 * hi])      = w0;
                *reinterpret_cast<uint2*>(&Pt[w][ql][8 + 4 * hi])  = w1;
                *reinterpret_cast<uint2*>(&Pt[w][ql][16 + 4 * hi]) = w2;
                *reinterpret_cast<uint2*>(&Pt[w][ql][24 + 4 * hi]) = w3;
            }

            // read PV B-frags: slot (hi,j) of frag sl = P[sl*16+8hi+j][q0+ql]
            union { uint32_t u[4]; bf16x8 v; } pa0, pa1;
            {
                uint2 r0 = *reinterpret_cast<const uint2*>(&Pt[w][ql][8 * hi]);
                uint2 r1 = *reinterpret_cast<const uint2*>(&Pt[w][ql][8 * hi + 4]);
                uint2 r2 = *reinterpret_cast<const uint2*>(&Pt[w][ql][16 + 8 * hi]);
                uint2 r3 = *reinterpret_cast<const uint2*>(&Pt[w][ql][16 + 8 * hi + 4]);
                pa0.u[0] = r0.x; pa0.u[1] = r0.y; pa0.u[2] = r1.x; pa0.u[3] = r1.y;
                pa1.u[0] = r2.x; pa1.u[1] = r2.y; pa1.u[2] = r3.x; pa1.u[3] = r3.y;
            }

            // O^T += V^T x P : acc col = q, row = d
            __builtin_amdgcn_s_setprio(1);
            o0 = mfma32(vf[0][0], pa0.v, o0);
            o0 = mfma32(vf[0][1], pa1.v, o0);
            o1 = mfma32(vf[1][0], pa0.v, o1);
            o1 = mfma32(vf[1][1], pa1.v, o1);
            __builtin_amdgcn_s_setprio(0);
        }
    }

    // combine partner partial sums
    lp += __shfl_xor(lp, 32);
    float inv = 1.0f / lp;

    // write: lane q = q0+ql ; reg r=g*4+j -> d = dblk*32 + 8*g + 4*hi + j
    __hip_bfloat16* yq = y + ((size_t)b * T + q0 + ql) * C + h * 64;
#pragma unroll
    for (int dblk = 0; dblk < 2; ++dblk) {
#pragma unroll
        for (int g = 0; g < 4; ++g) {
            union { __hip_bfloat16 h4[4]; uint2 v; } pkk;
#pragma unroll
            for (int r = 0; r < 4; ++r) {
                float val = (dblk ? o1[g * 4 + r] : o0[g * 4 + r]) * inv;
                pkk.h4[r] = __float2bfloat16(val);
            }
            *reinterpret_cast<uint2*>(yq + dblk * 32 + g * 8 + hi * 4) = pkk.v;
        }
    }
}

extern "C" void kernel_launch(void* const* d_in, const int* in_sizes, int n_in,
                              void* d_out, int out_size, void* d_ws, size_t ws_size,
                              hipStream_t stream) {
    const float* x      = (const float*)d_in[0];
    const float* W_attn = (const float*)d_in[1];
    const float* b_attn = (const float*)d_in[2];
    const float* W_proj = (const float*)d_in[3];
    const float* b_proj = (const float*)d_in[4];
    float* out = (float*)d_out;

    __hip_bfloat16* wsb = reinterpret_cast<__hip_bfloat16*>(d_ws);
    __hip_bfloat16* xb  = wsb;                              // 8192*1024
    __hip_bfloat16* WaT = xb + (size_t)8192 * 1024;         // 3072*1024
    __hip_bfloat16* WpT = WaT + (size_t)3072 * 1024;        // 1024*1024
    __hip_bfloat16* qd  = WpT + (size_t)1024 * 1024;        // 64*2048*64
    __hip_bfloat16* kd  = qd + (size_t)64 * 2048 * 64;
    __hip_bfloat16* vtd = kd + (size_t)64 * 2048 * 64;
    __hip_bfloat16* ya  = vtd + (size_t)64 * 2048 * 64;     // 8192*1024

    prep_kernel<<<4096 + 3072 + 1024, 256, 0, stream>>>(x, xb, W_attn, WaT, W_proj, WpT);
    gemm_qkv_kernel<<<dim3(64, 24), 256, 0, stream>>>(xb, WaT, b_attn, qd, kd, vtd);
    attn_kernel<<<512, 512, 0, stream>>>(qd, kd, vtd, ya);
    gemm_proj_kernel<<<dim3(64, 8), 256, 0, stream>>>(ya, WpT, b_proj, out);
}

// Round 21
// 168.497 us; speedup vs baseline: 1.1519x; 1.1519x over previous
//
#include <hip/hip_runtime.h>
#include <hip/hip_bf16.h>
#include <math.h>

// Problem: B=4, T=2048, C=1024, H=16, D=64
// out = proj( attention( x @ W_attn + b_attn ) ) + b_proj
// R21 = revert to R19 best-known configuration (169.3 us):
//   prep fused; gemm 128x128 BK=32 single-buffered (structure ceiling on this
//   shape -- BK=64/dbuf/256x256-4phase all regressed, branches closed);
//   attn v14 (KVBLK=64: v15's KVBLK=128 broke the V-tile swizzle involution ->
//   2.1M conflicts + occupancy drop, 55->97us. Reverted.)

typedef __bf16 bf16x8 __attribute__((ext_vector_type(8)));
typedef float f32x4 __attribute__((ext_vector_type(4)));
typedef float f32x16 __attribute__((ext_vector_type(16)));

__device__ __forceinline__ f32x4 mfma16(bf16x8 a, bf16x8 b, f32x4 c) {
    return __builtin_amdgcn_mfma_f32_16x16x32_bf16(a, b, c, 0, 0, 0);
}
__device__ __forceinline__ f32x16 mfma32(bf16x8 a, bf16x8 b, f32x16 c) {
    return __builtin_amdgcn_mfma_f32_32x32x16_bf16(a, b, c, 0, 0, 0);
}

#define GLOBAL_AS __attribute__((address_space(1)))
#define LDS_AS __attribute__((address_space(3)))

// async 16B/lane global->LDS (dest is wave-uniform base + lane*16)
__device__ __forceinline__ void async_copy16(const __hip_bfloat16* g, __hip_bfloat16* l) {
    __builtin_amdgcn_global_load_lds((const GLOBAL_AS uint32_t*)g, (LDS_AS uint32_t*)l, 16, 0, 0);
}

// pack two f32 -> 2 bf16 in one u32 (lo = first arg)
__device__ __forceinline__ uint32_t cvtpk(float lo, float hi) {
    uint32_t r;
    asm("v_cvt_pk_bf16_f32 %0, %1, %2" : "=v"(r) : "v"(lo), "v"(hi));
    return r;
}

// q is pre-scaled by 0.125*log2(e) so softmax exps are pure exp2
#define QSCL 0.18033688011112042f

// ---- fused preprocessing: cast x + transpose both weight matrices ----
__global__ __launch_bounds__(256) void prep_kernel(
    const float* __restrict__ x, __hip_bfloat16* __restrict__ xb,
    const float* __restrict__ Wa, __hip_bfloat16* __restrict__ WaT,
    const float* __restrict__ Wp, __hip_bfloat16* __restrict__ WpT) {
    int bid = blockIdx.x;
    if (bid < 4096) {
        int i = (bid * 256 + threadIdx.x) * 8;
        union { __hip_bfloat16 h[8]; uint4 v; } tmp;
#pragma unroll
        for (int j = 0; j < 8; ++j) tmp.h[j] = __float2bfloat16(x[i + j]);
        *reinterpret_cast<uint4*>(xb + i) = tmp.v;
        return;
    }
    __shared__ float tile[32][33];
    const float* in;
    __hip_bfloat16* out;
    int R, Cc, tx_blocks, tb;
    if (bid < 4096 + 3072) {
        tb = bid - 4096; in = Wa; out = WaT; R = 1024; Cc = 3072; tx_blocks = 96;
    } else {
        tb = bid - 4096 - 3072; in = Wp; out = WpT; R = 1024; Cc = 1024; tx_blocks = 32;
    }
    int c0 = (tb % tx_blocks) * 32, r0 = (tb / tx_blocks) * 32;
    int tx = threadIdx.x & 31, ty = threadIdx.x >> 5;  // ty 0..7
#pragma unroll
    for (int i = 0; i < 4; ++i) {
        int r = r0 + ty + i * 8;
        tile[ty + i * 8][tx] = in[(size_t)r * Cc + c0 + tx];
    }
    __syncthreads();
#pragma unroll
    for (int i = 0; i < 4; ++i) {
        int c = c0 + ty + i * 8;
        out[(size_t)c * R + r0 + tx] = __float2bfloat16(tile[tx][ty + i * 8]);
    }
}

// ================= m97-style 128x128 GEMM core (R15 form, proven 728 TF) =========
#define GEMM128_BODY(A_, Bt_, K_)                                                       \
    __shared__ __hip_bfloat16 As[128 * 32];                                             \
    __shared__ __hip_bfloat16 Bs[128 * 32];                                             \
    const int tid = threadIdx.x;                                                        \
    const int w = tid >> 6;                                                             \
    const int lr = tid & 15, lh = (tid & 63) >> 4;                                      \
    const int wr = w >> 1, wc = w & 1;                                                  \
    f32x4 zero = {0.f, 0.f, 0.f, 0.f};                                                  \
    f32x4 acc[4][4];                                                                    \
    _Pragma("unroll") for (int i = 0; i < 4; ++i)                                       \
        _Pragma("unroll") for (int j = 0; j < 4; ++j) acc[i][j] = zero;                 \
    for (int k0 = 0; k0 < (K_); k0 += 32) {                                             \
        _Pragma("unroll") for (int i = 0; i < 2; ++i) {                                 \
            int t = i * 256 + tid;                                                      \
            async_copy16((A_) + (size_t)(m0 + (t >> 2)) * (K_) + k0 + (t & 3) * 8,      \
                         As + (size_t)(i * 256 + w * 64) * 8);                          \
            async_copy16((Bt_) + (size_t)(n0 + (t >> 2)) * (K_) + k0 + (t & 3) * 8,     \
                         Bs + (size_t)(i * 256 + w * 64) * 8);                          \
        }                                                                               \
        __syncthreads();                                                                \
        bf16x8 af[4], bf[4];                                                            \
        _Pragma("unroll") for (int mf = 0; mf < 4; ++mf)                                \
            af[mf] = *reinterpret_cast<const bf16x8*>(                                  \
                &As[(wr * 64 + mf * 16 + lr) * 32 + lh * 8]);                           \
        _Pragma("unroll") for (int nf = 0; nf < 4; ++nf)                                \
            bf[nf] = *reinterpret_cast<const bf16x8*>(                                  \
                &Bs[(wc * 64 + nf * 16 + lr) * 32 + lh * 8]);                           \
        _Pragma("unroll") for (int mf = 0; mf < 4; ++mf)                                \
            _Pragma("unroll") for (int nf = 0; nf < 4; ++nf)                            \
                acc[mf][nf] = mfma16(af[mf], bf[nf], acc[mf][nf]);                      \
        __syncthreads();                                                                \
    }

// ---- QKV GEMM ----
__global__ __launch_bounds__(256) void gemm_qkv_kernel(
    const __hip_bfloat16* __restrict__ A, const __hip_bfloat16* __restrict__ Bt,
    const float* __restrict__ bias,
    __hip_bfloat16* __restrict__ qd, __hip_bfloat16* __restrict__ kd,
    __hip_bfloat16* __restrict__ vtd) {
    const int K = 1024;
    const int m0 = blockIdx.x * 128;
    const int n0 = blockIdx.y * 128;
    GEMM128_BODY(A, Bt, K)

    const int region = n0 >> 10;  // 0:q 1:k 2:v (block-uniform)
#pragma unroll
    for (int mf = 0; mf < 4; ++mf) {
#pragma unroll
        for (int nf = 0; nf < 4; ++nf) {
            int n = n0 + wc * 64 + nf * 16 + lr;
            float bv = bias[n];
            int mbase = m0 + wr * 64 + mf * 16 + 4 * lh;
            int bb = mbase >> 11;
            int t = mbase & 2047;
            int c = n & 1023, hh = c >> 6, dd = c & 63;
            if (region == 2) {
                union { __hip_bfloat16 h[4]; uint2 v; } pk;
#pragma unroll
                for (int r = 0; r < 4; ++r) pk.h[r] = __float2bfloat16(acc[mf][nf][r] + bv);
                *reinterpret_cast<uint2*>(
                    &vtd[(((size_t)bb * 16 + hh) * 64 + dd) * 2048 + t]) = pk.v;
            } else if (region == 0) {
#pragma unroll
                for (int r = 0; r < 4; ++r)
                    qd[(((size_t)bb * 16 + hh) * 2048 + t + r) * 64 + dd] =
                        __float2bfloat16((acc[mf][nf][r] + bv) * QSCL);
            } else {
#pragma unroll
                for (int r = 0; r < 4; ++r)
                    kd[(((size_t)bb * 16 + hh) * 2048 + t + r) * 64 + dd] =
                        __float2bfloat16(acc[mf][nf][r] + bv);
            }
        }
    }
}

// ---- proj GEMM ----
__global__ __launch_bounds__(256) void gemm_proj_kernel(
    const __hip_bfloat16* __restrict__ A, const __hip_bfloat16* __restrict__ Bt,
    const float* __restrict__ bias, float* __restrict__ out) {
    const int K = 1024, N = 1024;
    const int m0 = blockIdx.x * 128;
    const int n0 = blockIdx.y * 128;
    GEMM128_BODY(A, Bt, K)

#pragma unroll
    for (int nf = 0; nf < 4; ++nf) {
        int n = n0 + wc * 64 + nf * 16 + lr;
        float bv = bias[n];
#pragma unroll
        for (int mf = 0; mf < 4; ++mf) {
            int mbase = m0 + wr * 64 + mf * 16 + 4 * lh;
#pragma unroll
            for (int r = 0; r < 4; ++r)
                out[(size_t)(mbase + r) * N + n] = acc[mf][nf][r] + bv;
        }
    }
}

// ---- causal flash attention v14: 8-wave blocks, complementary q-tile pairing ----
__global__ __launch_bounds__(512) void attn_kernel(
    const __hip_bfloat16* __restrict__ q, const __hip_bfloat16* __restrict__ k,
    const __hip_bfloat16* __restrict__ vt, __hip_bfloat16* __restrict__ y) {
    const int T = 2048, D = 64, C = 1024;
    const float THR = 8.0f;

    // XCD swizzle: 64 consecutive wids per XCD = 8 whole heads
    int wid = ((int)blockIdx.x & 7) * 64 + ((int)blockIdx.x >> 3);
    int bh = wid >> 3;
    int qr = wid & 7;
    int q256 = (wid & 32) ? qr : 7 - qr;  // complementary across co-resident blocks
    int b = bh >> 4, h = bh & 15;
    int tid = threadIdx.x;
    int w = tid >> 6, l = tid & 63;
    int ql = l & 31, hi = l >> 5;

    __shared__ __hip_bfloat16 Ks[64 * 64];      // [kv][d], 128B rows, fold-swizzled
    __shared__ __hip_bfloat16 Vs[64 * 64];      // [d][kv], 128B rows, fold-swizzled
    __shared__ __hip_bfloat16 Pt[8][32][36];    // per-wave transposed P (R11-verified)

    const int q0 = q256 * 256 + w * 32;
    const __hip_bfloat16* kbh = k + (size_t)bh * T * D;
    const __hip_bfloat16* vbh = vt + (size_t)bh * D * T;

    // Q B-frags (hoisted): frag c covers d = c*16 + hi*8 .. +8, col = q0+ql
    bf16x8 qf[4];
#pragma unroll
    for (int c = 0; c < 4; ++c)
        qf[c] = *reinterpret_cast<const bf16x8*>(
            q + ((size_t)bh * T + q0 + ql) * D + c * 16 + hi * 8);

    f32x16 o0 = {}, o1 = {};
    float m = -INFINITY, lp = 0.f;

    const int lastSub = q0 >> 5;     // last active 32-kv sub-tile for this wave
    const int nt64 = 4 * q256 + 4;   // block-uniform outer tile count

    for (int t64 = 0; t64 < nt64; ++t64) {
        __syncthreads();  // previous tile's LDS reads complete before overwrite
        // ---- stage K (8KB) + V^T (8KB): 512 thr x (1 K slot + 1 V slot) ----
        {
            int slot = tid;                                        // 0..511
            int row = slot >> 3;                                   // 0..63
            int fold = ((row & 7) ^ (row >> 3)) & 7;
            int colb = ((slot & 7) * 16) ^ (fold << 4);            // byte in 128B row
            async_copy16(kbh + (size_t)(t64 * 64 + row) * 64 + (colb >> 1),
                         Ks + (size_t)(w * 64) * 8);
            async_copy16(vbh + (size_t)row * T + t64 * 64 + (colb >> 1),
                         Vs + (size_t)(w * 64) * 8);
        }
        __syncthreads();  // drains vmcnt, tile visible

#pragma unroll
        for (int sub = 0; sub < 2; ++sub) {
            const int is = t64 * 2 + sub;
            if (is > lastSub) break;   // wave-uniform causal skip
            // K frags from LDS: row = sub*32+ql, d-chunk c*16+hi*8
            bf16x8 kf[4];
            {
                int krow = sub * 32 + ql;
                int kfold = ((krow & 7) ^ (krow >> 3)) & 7;
                const char* KsB = reinterpret_cast<const char*>(Ks) + krow * 128;
#pragma unroll
                for (int c = 0; c < 4; ++c)
                    kf[c] = *reinterpret_cast<const bf16x8*>(
                        KsB + ((c * 32 + hi * 16) ^ (kfold << 4)));
            }

            __builtin_amdgcn_s_setprio(1);
            f32x16 s = {};
            s = mfma32(kf[0], qf[0], s);
            s = mfma32(kf[1], qf[1], s);
            s = mfma32(kf[2], qf[2], s);
            s = mfma32(kf[3], qf[3], s);
            __builtin_amdgcn_s_setprio(0);

            // V frags from LDS: row d = dblk*32+ql, kv-chunk sub*32 + sl*16 + hi*8
            bf16x8 vf[2][2];
#pragma unroll
            for (int dblk = 0; dblk < 2; ++dblk) {
                int vrow = dblk * 32 + ql;
                int vfold = ((vrow & 7) ^ (vrow >> 3)) & 7;
                const char* VsB = reinterpret_cast<const char*>(Vs) + vrow * 128;
#pragma unroll
                for (int sl = 0; sl < 2; ++sl)
                    vf[dblk][sl] = *reinterpret_cast<const bf16x8*>(
                        VsB + ((sub * 64 + sl * 32 + hi * 16) ^ (vfold << 4)));
            }

            // causal mask (diagonal sub-tile only): kv row > q row
            if (is == lastSub) {
#pragma unroll
                for (int r = 0; r < 16; ++r) {
                    int kvrow = (r & 3) + 8 * (r >> 2) + 4 * hi;
                    if (kvrow > ql) s[r] = -INFINITY;
                }
            }

            // row max: max3-friendly tree in-lane, then cross-half combine
            float mx;
            {
                float a = fmaxf(fmaxf(s[0], s[1]), s[2]);
                float bq = fmaxf(fmaxf(s[3], s[4]), s[5]);
                float c = fmaxf(fmaxf(s[6], s[7]), s[8]);
                float d = fmaxf(fmaxf(s[9], s[10]), s[11]);
                float e = fmaxf(fmaxf(s[12], s[13]), s[14]);
                mx = fmaxf(fmaxf(fmaxf(a, bq), fmaxf(c, d)), fmaxf(e, s[15]));
            }
            mx = fmaxf(mx, __shfl_xor(mx, 32));

            // defer-max: rescale only when growth exceeds THR
            if (!__all(mx - m <= THR)) {
                float mnew = fmaxf(m, mx);
                float al = __builtin_amdgcn_exp2f(m - mnew);
                m = mnew;
                lp *= al;
#pragma unroll
                for (int r = 0; r < 16; ++r) { o0[r] *= al; o1[r] *= al; }
            }

            // p = exp2(s - m)
#pragma unroll
            for (int r = 0; r < 16; ++r) s[r] = __builtin_amdgcn_exp2f(s[r] - m);

            // per-lane partial row sum (combined with partner at epilogue)
            lp += ((s[0] + s[1]) + (s[2] + s[3])) + ((s[4] + s[5]) + (s[6] + s[7])) +
                  (((s[8] + s[9]) + (s[10] + s[11])) + ((s[12] + s[13]) + (s[14] + s[15])));

            // stage P transposed: s[4g+r] = P[kv = 8g+4hi+r][q0+ql] -> Pt[ql][8g+4hi+r]
            {
                uint2 w0, w1, w2, w3;
                w0.x = cvtpk(s[0], s[1]);   w0.y = cvtpk(s[2], s[3]);
                w1.x = cvtpk(s[4], s[5]);   w1.y = cvtpk(s[6], s[7]);
                w2.x = cvtpk(s[8], s[9]);   w2.y = cvtpk(s[10], s[11]);
                w3.x = cvtpk(s[12], s[13]); w3.y = cvtpk(s[14], s[15]);
                *reinterpret_cast<uint2*>(&Pt[w][ql][4 * hi])      = w0;
                *reinterpret_cast<uint2*>(&Pt[w][ql][8 + 4 * hi])  = w1;
                *reinterpret_cast<uint2*>(&Pt[w][ql][16 + 4 * hi]) = w2;
                *reinterpret_cast<uint2*>(&Pt[w][ql][24 + 4 * hi]) = w3;
            }

            // read PV B-frags: slot (hi,j) of frag sl = P[sl*16+8hi+j][q0+ql]
            union { uint32_t u[4]; bf16x8 v; } pa0, pa1;
            {
                uint2 r0 = *reinterpret_cast<const uint2*>(&Pt[w][ql][8 * hi]);
                uint2 r1 = *reinterpret_cast<const uint2*>(&Pt[w][ql][8 * hi + 4]);
                uint2 r2 = *reinterpret_cast<const uint2*>(&Pt[w][ql][16 + 8 * hi]);
                uint2 r3 = *reinterpret_cast<const uint2*>(&Pt[w][ql][16 + 8 * hi + 4]);
                pa0.u[0] = r0.x; pa0.u[1] = r0.y; pa0.u[2] = r1.x; pa0.u[3] = r1.y;
                pa1.u[0] = r2.x; pa1.u[1] = r2.y; pa1.u[2] = r3.x; pa1.u[3] = r3.y;
            }

            // O^T += V^T x P : acc col = q, row = d
            __builtin_amdgcn_s_setprio(1);
            o0 = mfma32(vf[0][0], pa0.v, o0);
            o0 = mfma32(vf[0][1], pa1.v, o0);
            o1 = mfma32(vf[1][0], pa0.v, o1);
            o1 = mfma32(vf[1][1], pa1.v, o1);
            __builtin_amdgcn_s_setprio(0);
        }
    }

    // combine partner partial sums
    lp += __shfl_xor(lp, 32);
    float inv = 1.0f / lp;

    // write: lane q = q0+ql ; reg r=g*4+j -> d = dblk*32 + 8*g + 4*hi + j
    __hip_bfloat16* yq = y + ((size_t)b * T + q0 + ql) * C + h * 64;
#pragma unroll
    for (int dblk = 0; dblk < 2; ++dblk) {
#pragma unroll
        for (int g = 0; g < 4; ++g) {
            union { __hip_bfloat16 h4[4]; uint2 v; } pkk;
#pragma unroll
            for (int r = 0; r < 4; ++r) {
                float val = (dblk ? o1[g * 4 + r] : o0[g * 4 + r]) * inv;
                pkk.h4[r] = __float2bfloat16(val);
            }
            *reinterpret_cast<uint2*>(yq + dblk * 32 + g * 8 + hi * 4) = pkk.v;
        }
    }
}

extern "C" void kernel_launch(void* const* d_in, const int* in_sizes, int n_in,
                              void* d_out, int out_size, void* d_ws, size_t ws_size,
                              hipStream_t stream) {
    const float* x      = (const float*)d_in[0];
    const float* W_attn = (const float*)d_in[1];
    const float* b_attn = (const float*)d_in[2];
    const float* W_proj = (const float*)d_in[3];
    const float* b_proj = (const float*)d_in[4];
    float* out = (float*)d_out;

    __hip_bfloat16* wsb = reinterpret_cast<__hip_bfloat16*>(d_ws);
    __hip_bfloat16* xb  = wsb;                              // 8192*1024
    __hip_bfloat16* WaT = xb + (size_t)8192 * 1024;         // 3072*1024
    __hip_bfloat16* WpT = WaT + (size_t)3072 * 1024;        // 1024*1024
    __hip_bfloat16* qd  = WpT + (size_t)1024 * 1024;        // 64*2048*64
    __hip_bfloat16* kd  = qd + (size_t)64 * 2048 * 64;
    __hip_bfloat16* vtd = kd + (size_t)64 * 2048 * 64;
    __hip_bfloat16* ya  = vtd + (size_t)64 * 2048 * 64;     // 8192*1024

    prep_kernel<<<4096 + 3072 + 1024, 256, 0, stream>>>(x, xb, W_attn, WaT, W_proj, WpT);
    gemm_qkv_kernel<<<dim3(64, 24), 256, 0, stream>>>(xb, WaT, b_attn, qd, kd, vtd);
    attn_kernel<<<512, 512, 0, stream>>>(qd, kd, vtd, ya);
    gemm_proj_kernel<<<dim3(64, 8), 256, 0, stream>>>(ya, WpT, b_proj, out);
}

// Round 22
// 166.232 us; speedup vs baseline: 1.1676x; 1.0136x over previous
//
#include <hip/hip_runtime.h>
#include <hip/hip_bf16.h>
#include <math.h>

// Problem: B=4, T=2048, C=1024, H=16, D=64
// out = proj( attention( x @ W_attn + b_attn ) ) + b_proj
// R22 = R21 + qkv rebuilt as 256x256 fine-grained 4-phase/K-tile pipeline
// (m201-style: B-frags once per K-tile, 1 barrier/phase, counted vmcnt ledger).

typedef __bf16 bf16x8 __attribute__((ext_vector_type(8)));
typedef float f32x4 __attribute__((ext_vector_type(4)));
typedef float f32x16 __attribute__((ext_vector_type(16)));

__device__ __forceinline__ f32x4 mfma16(bf16x8 a, bf16x8 b, f32x4 c) {
    return __builtin_amdgcn_mfma_f32_16x16x32_bf16(a, b, c, 0, 0, 0);
}
__device__ __forceinline__ f32x16 mfma32(bf16x8 a, bf16x8 b, f32x16 c) {
    return __builtin_amdgcn_mfma_f32_32x32x16_bf16(a, b, c, 0, 0, 0);
}

#define GLOBAL_AS __attribute__((address_space(1)))
#define LDS_AS __attribute__((address_space(3)))

// async 16B/lane global->LDS (dest is wave-uniform base + lane*16)
__device__ __forceinline__ void async_copy16(const __hip_bfloat16* g, __hip_bfloat16* l) {
    __builtin_amdgcn_global_load_lds((const GLOBAL_AS uint32_t*)g, (LDS_AS uint32_t*)l, 16, 0, 0);
}

// pack two f32 -> 2 bf16 in one u32 (lo = first arg)
__device__ __forceinline__ uint32_t cvtpk(float lo, float hi) {
    uint32_t r;
    asm("v_cvt_pk_bf16_f32 %0, %1, %2" : "=v"(r) : "v"(lo), "v"(hi));
    return r;
}

// q is pre-scaled by 0.125*log2(e) so softmax exps are pure exp2
#define QSCL 0.18033688011112042f

// ---- fused preprocessing: cast x + transpose both weight matrices ----
__global__ __launch_bounds__(256) void prep_kernel(
    const float* __restrict__ x, __hip_bfloat16* __restrict__ xb,
    const float* __restrict__ Wa, __hip_bfloat16* __restrict__ WaT,
    const float* __restrict__ Wp, __hip_bfloat16* __restrict__ WpT) {
    int bid = blockIdx.x;
    if (bid < 4096) {
        int i = (bid * 256 + threadIdx.x) * 8;
        union { __hip_bfloat16 h[8]; uint4 v; } tmp;
#pragma unroll
        for (int j = 0; j < 8; ++j) tmp.h[j] = __float2bfloat16(x[i + j]);
        *reinterpret_cast<uint4*>(xb + i) = tmp.v;
        return;
    }
    __shared__ float tile[32][33];
    const float* in;
    __hip_bfloat16* out;
    int R, Cc, tx_blocks, tb;
    if (bid < 4096 + 3072) {
        tb = bid - 4096; in = Wa; out = WaT; R = 1024; Cc = 3072; tx_blocks = 96;
    } else {
        tb = bid - 4096 - 3072; in = Wp; out = WpT; R = 1024; Cc = 1024; tx_blocks = 32;
    }
    int c0 = (tb % tx_blocks) * 32, r0 = (tb / tx_blocks) * 32;
    int tx = threadIdx.x & 31, ty = threadIdx.x >> 5;  // ty 0..7
#pragma unroll
    for (int i = 0; i < 4; ++i) {
        int r = r0 + ty + i * 8;
        tile[ty + i * 8][tx] = in[(size_t)r * Cc + c0 + tx];
    }
    __syncthreads();
#pragma unroll
    for (int i = 0; i < 4; ++i) {
        int c = c0 + ty + i * 8;
        out[(size_t)c * R + r0 + tx] = __float2bfloat16(tile[tx][ty + i * 8]);
    }
}

// ================= m97-style 128x128 GEMM core (proj; proven) =================
#define GEMM128_BODY(A_, Bt_, K_)                                                       \
    __shared__ __hip_bfloat16 As[128 * 32];                                             \
    __shared__ __hip_bfloat16 Bs[128 * 32];                                             \
    const int tid = threadIdx.x;                                                        \
    const int w = tid >> 6;                                                             \
    const int lr = tid & 15, lh = (tid & 63) >> 4;                                      \
    const int wr = w >> 1, wc = w & 1;                                                  \
    f32x4 zero = {0.f, 0.f, 0.f, 0.f};                                                  \
    f32x4 acc[4][4];                                                                    \
    _Pragma("unroll") for (int i = 0; i < 4; ++i)                                       \
        _Pragma("unroll") for (int j = 0; j < 4; ++j) acc[i][j] = zero;                 \
    for (int k0 = 0; k0 < (K_); k0 += 32) {                                             \
        _Pragma("unroll") for (int i = 0; i < 2; ++i) {                                 \
            int t = i * 256 + tid;                                                      \
            async_copy16((A_) + (size_t)(m0 + (t >> 2)) * (K_) + k0 + (t & 3) * 8,      \
                         As + (size_t)(i * 256 + w * 64) * 8);                          \
            async_copy16((Bt_) + (size_t)(n0 + (t >> 2)) * (K_) + k0 + (t & 3) * 8,     \
                         Bs + (size_t)(i * 256 + w * 64) * 8);                          \
        }                                                                               \
        __syncthreads();                                                                \
        bf16x8 af[4], bf[4];                                                            \
        _Pragma("unroll") for (int mf = 0; mf < 4; ++mf)                                \
            af[mf] = *reinterpret_cast<const bf16x8*>(                                  \
                &As[(wr * 64 + mf * 16 + lr) * 32 + lh * 8]);                           \
        _Pragma("unroll") for (int nf = 0; nf < 4; ++nf)                                \
            bf[nf] = *reinterpret_cast<const bf16x8*>(                                  \
                &Bs[(wc * 64 + nf * 16 + lr) * 32 + lh * 8]);                           \
        _Pragma("unroll") for (int mf = 0; mf < 4; ++mf)                                \
            _Pragma("unroll") for (int nf = 0; nf < 4; ++nf)                            \
                acc[mf][nf] = mfma16(af[mf], bf[nf], acc[mf][nf]);                      \
        __syncthreads();                                                                \
    }

// one phase of the 256x256 qkv pipeline: reads 2 mf-rows x 2 kk A-frags,
// issues STAGE, fences, 16 MFMA, optional WAIT, barrier.
#define QKV_PHASE(d_, MF0_, STAGE_STMT, WAIT_STMT)                                      \
    {                                                                                   \
        bf16x8 a00 = readA(d_, (MF0_), 0), a01 = readA(d_, (MF0_), 1);                  \
        bf16x8 a10 = readA(d_, (MF0_) + 1, 0), a11 = readA(d_, (MF0_) + 1, 1);          \
        STAGE_STMT;                                                                     \
        asm volatile("s_waitcnt lgkmcnt(0)" ::: "memory");                              \
        __builtin_amdgcn_sched_barrier(0);                                              \
        __builtin_amdgcn_s_setprio(1);                                                  \
        _Pragma("unroll") for (int nf = 0; nf < 4; ++nf) {                              \
            acc[(MF0_)][nf]     = mfma16(a00, bfr[nf][0], acc[(MF0_)][nf]);             \
            acc[(MF0_)][nf]     = mfma16(a01, bfr[nf][1], acc[(MF0_)][nf]);             \
            acc[(MF0_) + 1][nf] = mfma16(a10, bfr[nf][0], acc[(MF0_) + 1][nf]);         \
            acc[(MF0_) + 1][nf] = mfma16(a11, bfr[nf][1], acc[(MF0_) + 1][nf]);         \
        }                                                                               \
        __builtin_amdgcn_s_setprio(0);                                                  \
        WAIT_STMT;                                                                      \
        __builtin_amdgcn_s_barrier();                                                   \
    }

// ---- QKV GEMM: 256x256, BK=64, fine 4-phase/K-tile counted-vmcnt pipeline ----
// 512 thr = 8 waves (2M x 4N); wave = 128x64 out = acc[8][4].
// LDS S[2(buf)][2(A/B)][256 rows][64 k], 128B rows, swizzle byte ^= (row&7)<<4
// (both-sides; R18-verified 0-conflict). Stage granularity = 64-row quarter
// (1 load/thread); order per tile: Bq0,Bq1 / Bq2,Bq3 / Aq0,Aq2 / Aq1,Aq3.
// Steady-state ledger (per-thread, 1 load per stage call):
//   end p1: outstanding {Aq1,Aq3(t), Bq01,Bq23(t+1)}=6 -> vmcnt(4) retires
//           Aq1,Aq3(t) needed by p2/p3 reads.
//   end p3: outstanding 8 -> vmcnt(2) retires Bq0..3+Aq0,Aq2(t+1) for next p0.
// Last tile: vmcnt(0) at p1 (drain), nothing at p3.
__global__ __launch_bounds__(512, 2) void gemm_qkv_kernel(
    const __hip_bfloat16* __restrict__ A, const __hip_bfloat16* __restrict__ Bt,
    const float* __restrict__ bias,
    __hip_bfloat16* __restrict__ qd, __hip_bfloat16* __restrict__ kd,
    __hip_bfloat16* __restrict__ vtd) {
    const int K = 1024, nt = 16;
    const int m0 = blockIdx.x * 256;
    const int n0 = blockIdx.y * 256;
    const int tid = threadIdx.x;
    const int w = tid >> 6, l = tid & 63;
    const int lr = l & 15, lh = l >> 4;
    const int wr = w >> 2, wcn = w & 3;

    __shared__ __hip_bfloat16 S[2][2][256 * 64];  // [buf][A=0/B=1], 128 KB

    f32x4 acc[8][4] = {};

    // stage one 64-row quarter (8KB, 1 load/thread) of A(ab=0)/B(ab=1)
    auto stageQ = [&](int e, int ab, int qq, int t) {
        const __hip_bfloat16* src = ab ? Bt + (size_t)(n0 + qq * 64) * K
                                       : A + (size_t)(m0 + qq * 64) * K;
        int row = tid >> 3;                               // 0..63
        int colb = ((tid & 7) * 16) ^ ((row & 7) << 4);   // pre-swizzled source
        async_copy16(src + (size_t)row * K + t * 64 + (colb >> 1),
                     &S[e][ab][qq * 64 * 64 + w * 512]);
    };
    auto readA = [&](int d, int mf, int kk) -> bf16x8 {
        int row = wr * 128 + mf * 16 + lr;
        int colb = (kk * 64 + lh * 16) ^ ((lr & 7) << 4);
        return *reinterpret_cast<const bf16x8*>(
            reinterpret_cast<const char*>(&S[d][0][0]) + row * 128 + colb);
    };
    auto readB = [&](int d, int nf, int kk) -> bf16x8 {
        int row = wcn * 64 + nf * 16 + lr;
        int colb = (kk * 64 + lh * 16) ^ ((lr & 7) << 4);
        return *reinterpret_cast<const bf16x8*>(
            reinterpret_cast<const char*>(&S[d][1][0]) + row * 128 + colb);
    };

    // prologue: tile 0 in ledger order; Aq1,Aq3 stay in flight (vmcnt(2))
    stageQ(0, 1, 0, 0); stageQ(0, 1, 1, 0); stageQ(0, 1, 2, 0); stageQ(0, 1, 3, 0);
    stageQ(0, 0, 0, 0); stageQ(0, 0, 2, 0); stageQ(0, 0, 1, 0); stageQ(0, 0, 3, 0);
    asm volatile("s_waitcnt vmcnt(2)" ::: "memory");
    __builtin_amdgcn_s_barrier();

    for (int t = 0; t < nt; ++t) {
        const int d = t & 1, e = d ^ 1;
        const bool nxt = (t + 1 < nt);
        // B-frags once per K-tile (reused across all 4 phases)
        bf16x8 bfr[4][2];
#pragma unroll
        for (int nf = 0; nf < 4; ++nf) {
            bfr[nf][0] = readB(d, nf, 0);
            bfr[nf][1] = readB(d, nf, 1);
        }
        QKV_PHASE(d, 0,
            { if (nxt) { stageQ(e, 1, 0, t + 1); stageQ(e, 1, 1, t + 1); } },
            {});
        QKV_PHASE(d, 2,
            { if (nxt) { stageQ(e, 1, 2, t + 1); stageQ(e, 1, 3, t + 1); } },
            { if (nxt) asm volatile("s_waitcnt vmcnt(4)" ::: "memory");
              else     asm volatile("s_waitcnt vmcnt(0)" ::: "memory"); });
        QKV_PHASE(d, 4,
            { if (nxt) { stageQ(e, 0, 0, t + 1); stageQ(e, 0, 2, t + 1); } },
            {});
        QKV_PHASE(d, 6,
            { if (nxt) { stageQ(e, 0, 1, t + 1); stageQ(e, 0, 3, t + 1); } },
            { if (nxt) asm volatile("s_waitcnt vmcnt(2)" ::: "memory"); });
    }

    // epilogue: region-split scatter (verified R18)
    const int region = n0 >> 10;  // block-uniform
#pragma unroll
    for (int mf = 0; mf < 8; ++mf) {
#pragma unroll
        for (int nf = 0; nf < 4; ++nf) {
            int n = n0 + wcn * 64 + nf * 16 + lr;
            float bv = bias[n];
            int mbase = m0 + wr * 128 + mf * 16 + 4 * lh;
            int bb = mbase >> 11;
            int tt = mbase & 2047;
            int c = n & 1023, hh = c >> 6, dd = c & 63;
            if (region == 2) {
                union { __hip_bfloat16 h[4]; uint2 v; } pk;
#pragma unroll
                for (int r = 0; r < 4; ++r) pk.h[r] = __float2bfloat16(acc[mf][nf][r] + bv);
                *reinterpret_cast<uint2*>(
                    &vtd[(((size_t)bb * 16 + hh) * 64 + dd) * 2048 + tt]) = pk.v;
            } else if (region == 0) {
#pragma unroll
                for (int r = 0; r < 4; ++r)
                    qd[(((size_t)bb * 16 + hh) * 2048 + tt + r) * 64 + dd] =
                        __float2bfloat16((acc[mf][nf][r] + bv) * QSCL);
            } else {
#pragma unroll
                for (int r = 0; r < 4; ++r)
                    kd[(((size_t)bb * 16 + hh) * 2048 + tt + r) * 64 + dd] =
                        __float2bfloat16(acc[mf][nf][r] + bv);
            }
        }
    }
}

// ---- proj GEMM (128² single-buffered, proven) ----
__global__ __launch_bounds__(256) void gemm_proj_kernel(
    const __hip_bfloat16* __restrict__ A, const __hip_bfloat16* __restrict__ Bt,
    const float* __restrict__ bias, float* __restrict__ out) {
    const int K = 1024, N = 1024;
    const int m0 = blockIdx.x * 128;
    const int n0 = blockIdx.y * 128;
    GEMM128_BODY(A, Bt, K)

#pragma unroll
    for (int nf = 0; nf < 4; ++nf) {
        int n = n0 + wc * 64 + nf * 16 + lr;
        float bv = bias[n];
#pragma unroll
        for (int mf = 0; mf < 4; ++mf) {
            int mbase = m0 + wr * 64 + mf * 16 + 4 * lh;
#pragma unroll
            for (int r = 0; r < 4; ++r)
                out[(size_t)(mbase + r) * N + n] = acc[mf][nf][r] + bv;
        }
    }
}

// ---- causal flash attention v14 (unchanged, best-measured) ----
__global__ __launch_bounds__(512) void attn_kernel(
    const __hip_bfloat16* __restrict__ q, const __hip_bfloat16* __restrict__ k,
    const __hip_bfloat16* __restrict__ vt, __hip_bfloat16* __restrict__ y) {
    const int T = 2048, D = 64, C = 1024;
    const float THR = 8.0f;

    int wid = ((int)blockIdx.x & 7) * 64 + ((int)blockIdx.x >> 3);
    int bh = wid >> 3;
    int qr = wid & 7;
    int q256 = (wid & 32) ? qr : 7 - qr;
    int b = bh >> 4, h = bh & 15;
    int tid = threadIdx.x;
    int w = tid >> 6, l = tid & 63;
    int ql = l & 31, hi = l >> 5;

    __shared__ __hip_bfloat16 Ks[64 * 64];
    __shared__ __hip_bfloat16 Vs[64 * 64];
    __shared__ __hip_bfloat16 Pt[8][32][36];

    const int q0 = q256 * 256 + w * 32;
    const __hip_bfloat16* kbh = k + (size_t)bh * T * D;
    const __hip_bfloat16* vbh = vt + (size_t)bh * D * T;

    bf16x8 qf[4];
#pragma unroll
    for (int c = 0; c < 4; ++c)
        qf[c] = *reinterpret_cast<const bf16x8*>(
            q + ((size_t)bh * T + q0 + ql) * D + c * 16 + hi * 8);

    f32x16 o0 = {}, o1 = {};
    float m = -INFINITY, lp = 0.f;

    const int lastSub = q0 >> 5;
    const int nt64 = 4 * q256 + 4;

    for (int t64 = 0; t64 < nt64; ++t64) {
        __syncthreads();
        {
            int slot = tid;
            int row = slot >> 3;
            int fold = ((row & 7) ^ (row >> 3)) & 7;
            int colb = ((slot & 7) * 16) ^ (fold << 4);
            async_copy16(kbh + (size_t)(t64 * 64 + row) * 64 + (colb >> 1),
                         Ks + (size_t)(w * 64) * 8);
            async_copy16(vbh + (size_t)row * T + t64 * 64 + (colb >> 1),
                         Vs + (size_t)(w * 64) * 8);
        }
        __syncthreads();

#pragma unroll
        for (int sub = 0; sub < 2; ++sub) {
            const int is = t64 * 2 + sub;
            if (is > lastSub) break;
            bf16x8 kf[4];
            {
                int krow = sub * 32 + ql;
                int kfold = ((krow & 7) ^ (krow >> 3)) & 7;
                const char* KsB = reinterpret_cast<const char*>(Ks) + krow * 128;
#pragma unroll
                for (int c = 0; c < 4; ++c)
                    kf[c] = *reinterpret_cast<const bf16x8*>(
                        KsB + ((c * 32 + hi * 16) ^ (kfold << 4)));
            }

            __builtin_amdgcn_s_setprio(1);
            f32x16 s = {};
            s = mfma32(kf[0], qf[0], s);
            s = mfma32(kf[1], qf[1], s);
            s = mfma32(kf[2], qf[2], s);
            s = mfma32(kf[3], qf[3], s);
            __builtin_amdgcn_s_setprio(0);

            bf16x8 vf[2][2];
#pragma unroll
            for (int dblk = 0; dblk < 2; ++dblk) {
                int vrow = dblk * 32 + ql;
                int vfold = ((vrow & 7) ^ (vrow >> 3)) & 7;
                const char* VsB = reinterpret_cast<const char*>(Vs) + vrow * 128;
#pragma unroll
                for (int sl = 0; sl < 2; ++sl)
                    vf[dblk][sl] = *reinterpret_cast<const bf16x8*>(
                        VsB + ((sub * 64 + sl * 32 + hi * 16) ^ (vfold << 4)));
            }

            if (is == lastSub) {
#pragma unroll
                for (int r = 0; r < 16; ++r) {
                    int kvrow = (r & 3) + 8 * (r >> 2) + 4 * hi;
                    if (kvrow > ql) s[r] = -INFINITY;
                }
            }

            float mx;
            {
                float a = fmaxf(fmaxf(s[0], s[1]), s[2]);
                float bq = fmaxf(fmaxf(s[3], s[4]), s[5]);
                float c = fmaxf(fmaxf(s[6], s[7]), s[8]);
                float d = fmaxf(fmaxf(s[9], s[10]), s[11]);
                float e = fmaxf(fmaxf(s[12], s[13]), s[14]);
                mx = fmaxf(fmaxf(fmaxf(a, bq), fmaxf(c, d)), fmaxf(e, s[15]));
            }
            mx = fmaxf(mx, __shfl_xor(mx, 32));

            if (!__all(mx - m <= THR)) {
                float mnew = fmaxf(m, mx);
                float al = __builtin_amdgcn_exp2f(m - mnew);
                m = mnew;
                lp *= al;
#pragma unroll
                for (int r = 0; r < 16; ++r) { o0[r] *= al; o1[r] *= al; }
            }

#pragma unroll
            for (int r = 0; r < 16; ++r) s[r] = __builtin_amdgcn_exp2f(s[r] - m);

            lp += ((s[0] + s[1]) + (s[2] + s[3])) + ((s[4] + s[5]) + (s[6] + s[7])) +
                  (((s[8] + s[9]) + (s[10] + s[11])) + ((s[12] + s[13]) + (s[14] + s[15])));

            {
                uint2 w0, w1, w2, w3;
                w0.x = cvtpk(s[0], s[1]);   w0.y = cvtpk(s[2], s[3]);
                w1.x = cvtpk(s[4], s[5]);   w1.y = cvtpk(s[6], s[7]);
                w2.x = cvtpk(s[8], s[9]);   w2.y = cvtpk(s[10], s[11]);
                w3.x = cvtpk(s[12], s[13]); w3.y = cvtpk(s[14], s[15]);
                *reinterpret_cast<uint2*>(&Pt[w][ql][4 * hi])      = w0;
                *reinterpret_cast<uint2*>(&Pt[w][ql][8 + 4 * hi])  = w1;
                *reinterpret_cast<uint2*>(&Pt[w][ql][16 + 4 * hi]) = w2;
                *reinterpret_cast<uint2*>(&Pt[w][ql][24 + 4 * hi]) = w3;
            }

            union { uint32_t u[4]; bf16x8 v; } pa0, pa1;
            {
                uint2 r0 = *reinterpret_cast<const uint2*>(&Pt[w][ql][8 * hi]);
                uint2 r1 = *reinterpret_cast<const uint2*>(&Pt[w][ql][8 * hi + 4]);
                uint2 r2 = *reinterpret_cast<const uint2*>(&Pt[w][ql][16 + 8 * hi]);
                uint2 r3 = *reinterpret_cast<const uint2*>(&Pt[w][ql][16 + 8 * hi + 4]);
                pa0.u[0] = r0.x; pa0.u[1] = r0.y; pa0.u[2] = r1.x; pa0.u[3] = r1.y;
                pa1.u[0] = r2.x; pa1.u[1] = r2.y; pa1.u[2] = r3.x; pa1.u[3] = r3.y;
            }

            __builtin_amdgcn_s_setprio(1);
            o0 = mfma32(vf[0][0], pa0.v, o0);
            o0 = mfma32(vf[0][1], pa1.v, o0);
            o1 = mfma32(vf[1][0], pa0.v, o1);
            o1 = mfma32(vf[1][1], pa1.v, o1);
            __builtin_amdgcn_s_setprio(0);
        }
    }

    lp += __shfl_xor(lp, 32);
    float inv = 1.0f / lp;

    __hip_bfloat16* yq = y + ((size_t)b * T + q0 + ql) * C + h * 64;
#pragma unroll
    for (int dblk = 0; dblk < 2; ++dblk) {
#pragma unroll
        for (int g = 0; g < 4; ++g) {
            union { __hip_bfloat16 h4[4]; uint2 v; } pkk;
#pragma unroll
            for (int r = 0; r < 4; ++r) {
                float val = (dblk ? o1[g * 4 + r] : o0[g * 4 + r]) * inv;
                pkk.h4[r] = __float2bfloat16(val);
            }
            *reinterpret_cast<uint2*>(yq + dblk * 32 + g * 8 + hi * 4) = pkk.v;
        }
    }
}

extern "C" void kernel_launch(void* const* d_in, const int* in_sizes, int n_in,
                              void* d_out, int out_size, void* d_ws, size_t ws_size,
                              hipStream_t stream) {
    const float* x      = (const float*)d_in[0];
    const float* W_attn = (const float*)d_in[1];
    const float* b_attn = (const float*)d_in[2];
    const float* W_proj = (const float*)d_in[3];
    const float* b_proj = (const float*)d_in[4];
    float* out = (float*)d_out;

    __hip_bfloat16* wsb = reinterpret_cast<__hip_bfloat16*>(d_ws);
    __hip_bfloat16* xb  = wsb;                              // 8192*1024
    __hip_bfloat16* WaT = xb + (size_t)8192 * 1024;         // 3072*1024
    __hip_bfloat16* WpT = WaT + (size_t)3072 * 1024;        // 1024*1024
    __hip_bfloat16* qd  = WpT + (size_t)1024 * 1024;        // 64*2048*64
    __hip_bfloat16* kd  = qd + (size_t)64 * 2048 * 64;
    __hip_bfloat16* vtd = kd + (size_t)64 * 2048 * 64;
    __hip_bfloat16* ya  = vtd + (size_t)64 * 2048 * 64;     // 8192*1024

    prep_kernel<<<4096 + 3072 + 1024, 256, 0, stream>>>(x, xb, W_attn, WaT, W_proj, WpT);
    gemm_qkv_kernel<<<dim3(32, 12), 512, 0, stream>>>(xb, WaT, b_attn, qd, kd, vtd);
    attn_kernel<<<512, 512, 0, stream>>>(qd, kd, vtd, ya);
    gemm_proj_kernel<<<dim3(64, 8), 256, 0, stream>>>(ya, WpT, b_proj, out);
}